// Round 6
// baseline (359.416 us; speedup 1.0000x reference)
//
#include <hip/hip_runtime.h>
#include <stdint.h>

#define IN_F 4096
#define OUT_F 4096
#define NTRI 2016

typedef unsigned short u16;
typedef __attribute__((ext_vector_type(8))) short short8;
typedef __attribute__((ext_vector_type(4))) float f32x4;
typedef __attribute__((ext_vector_type(16))) float f32x16;
typedef __attribute__((ext_vector_type(4))) int i32x4;
typedef __attribute__((ext_vector_type(4))) unsigned short u16x4;

__device__ __forceinline__ u16 f2bf(float f) {
    uint32_t u = __builtin_bit_cast(uint32_t, f);
    u = (u + 0x7FFFu + ((u >> 16) & 1u)) >> 16;   // round-to-nearest-even
    return (u16)u;
}

__device__ __forceinline__ void gload16(const void* g, void* l) {
    __builtin_amdgcn_global_load_lds((__attribute__((address_space(1))) void*)g,
                                     (__attribute__((address_space(3))) void*)l,
                                     16, 0, 0);
}

#define FENCE() asm volatile("" ::: "memory")

// ---------------- pass 1: pinv_out[perm_out[i]] = i ----------------
__global__ void k_inv_perm(const int* __restrict__ perm_out, int* __restrict__ pinv_out) {
    int i = blockIdx.x * 256 + threadIdx.x;
    if (i < OUT_F) pinv_out[perm_out[i]] = i;
}

// ---------------- pass 2: Cayley-Neumann, 4x4 register-blocked ----------------
__global__ __launch_bounds__(256) void k_cayley(const float* __restrict__ Ro,
                                                const float* __restrict__ Ri,
                                                float* __restrict__ Rout,
                                                u16* __restrict__ QT16,
                                                u16* __restrict__ P16) {
    __shared__ __align__(16) float Qs[64 * 64];
    __shared__ __align__(16) float Ps[64 * 68];
    __shared__ __align__(16) float Ts[64 * 68];
    int b = blockIdx.x;
    const float* vec = (b < 64) ? (Ro + (size_t)b * NTRI) : (Ri + (size_t)(b - 64) * NTRI);
    int t = threadIdx.x;
    int tr = t >> 4, tc = t & 15;
#pragma unroll
    for (int e = 0; e < 16; ++e) {
        int el = e * 256 + t;
        int i = el >> 6, j = el & 63;
        float q = 0.f;
        if (i < j) q =  vec[i * 63 - (i * (i - 1)) / 2 + (j - i - 1)];
        if (i > j) q = -vec[j * 63 - (j * (j - 1)) / 2 + (i - j - 1)];
        Qs[el] = q;
    }
    __syncthreads();
    float a2[4][4], a3[4][4], a4[4][4];
#pragma unroll
    for (int i = 0; i < 4; ++i)
#pragma unroll
        for (int j = 0; j < 4; ++j) { a2[i][j] = 0.f; a3[i][j] = 0.f; a4[i][j] = 0.f; }
    for (int k = 0; k < 64; ++k) {
        f32x4 qa = *(const f32x4*)&Qs[k * 64 + tr * 4];
        f32x4 qb = *(const f32x4*)&Qs[k * 64 + tc * 4];
#pragma unroll
        for (int i = 0; i < 4; ++i)
#pragma unroll
            for (int j = 0; j < 4; ++j) a2[i][j] -= qa[i] * qb[j];
    }
#pragma unroll
    for (int i = 0; i < 4; ++i)
#pragma unroll
        for (int j = 0; j < 4; ++j) Ps[(tr * 4 + i) * 68 + tc * 4 + j] = a2[i][j];
    __syncthreads();
    for (int k = 0; k < 64; ++k) {
        f32x4 pa = *(const f32x4*)&Ps[k * 68 + tr * 4];
        f32x4 qb = *(const f32x4*)&Qs[k * 64 + tc * 4];
#pragma unroll
        for (int i = 0; i < 4; ++i)
#pragma unroll
            for (int j = 0; j < 4; ++j) a3[i][j] += pa[i] * qb[j];
    }
#pragma unroll
    for (int i = 0; i < 4; ++i)
#pragma unroll
        for (int j = 0; j < 4; ++j) Ts[(tc * 4 + j) * 68 + tr * 4 + i] = -a3[i][j];  // Ts[k][i]=Q3[k][i]
    __syncthreads();
    for (int k = 0; k < 64; ++k) {
        f32x4 ta = *(const f32x4*)&Ts[k * 68 + tr * 4];
        f32x4 qb = *(const f32x4*)&Qs[k * 64 + tc * 4];
#pragma unroll
        for (int i = 0; i < 4; ++i)
#pragma unroll
            for (int j = 0; j < 4; ++j) a4[i][j] -= ta[i] * qb[j];
    }
    if (b < 64) {
        float* dst = Rout + (size_t)b * 4096;
        u16* qt = QT16 + (size_t)b * 4096;
#pragma unroll
        for (int i = 0; i < 4; ++i) {
            int gi = tr * 4 + i;
            f32x4 q4 = *(const f32x4*)&Qs[gi * 64 + tc * 4];
            f32x4 o;
#pragma unroll
            for (int j = 0; j < 4; ++j) {
                int gj = tc * 4 + j;
                o[j] = 2.f * (q4[j] + a2[i][j] + a3[i][j] + a4[i][j]) + ((gi == gj) ? 1.f : 0.f);
            }
            *(f32x4*)&dst[gi * 64 + tc * 4] = o;
#pragma unroll
            for (int j = 0; j < 4; ++j) qt[(tc * 4 + j) * 64 + gi] = f2bf(o[j]);  // QT[d][c]=R[c][d]
        }
    } else {
        u16* p = P16 + (size_t)(b - 64) * 4096;
#pragma unroll
        for (int i = 0; i < 4; ++i) {
            int gi = tr * 4 + i;
            f32x4 q4 = *(const f32x4*)&Qs[gi * 64 + tc * 4];
            u16x4 pk;
#pragma unroll
            for (int j = 0; j < 4; ++j) {
                int gj = tc * 4 + j;
                float v = 2.f * (q4[j] + a2[i][j] + a3[i][j] + a4[i][j]) + ((gi == gj) ? 1.f : 0.f);
                pk[j] = f2bf(v);
            }
            *(u16x4*)&p[gi * 64 + tc * 4] = pk;
        }
    }
}

// ---------------- pass 3: fused bias: bfinal[j] = (bias . R_out_bd)[perm_out[j]] --------
__global__ void k_bias(const float* __restrict__ bias, const float* __restrict__ Rout,
                       const int* __restrict__ perm_out, float* __restrict__ bfinal) {
    int j = blockIdx.x * 256 + threadIdx.x;
    if (j >= OUT_F) return;
    int o = perm_out[j];
    int r = o >> 6, d = o & 63;
    const float* Rb = Rout + (size_t)r * 4096;
    const float* bb = bias + r * 64;
    float s = 0.f;
    for (int c = 0; c < 64; ++c) s += bb[c] * Rb[c * 64 + d];
    bfinal[j] = s;
}

// ---------------- pass 4: fused MFMA fold ----------------
__global__ __launch_bounds__(256) void k_fold(const float* __restrict__ W,
                                              const u16* __restrict__ P16,
                                              const u16* __restrict__ QT16,
                                              const int* __restrict__ pinv_out,
                                              u16* __restrict__ Ctp) {
    __shared__ __align__(16) u16 Wst[128 * 64];   // swizzled bf16 W tile
    __shared__ __align__(16) u16 Ut[64 * 128];    // Ut[i][c] swizzled
    const int s = blockIdx.x;
    const int br = blockIdx.y;
    const int t = threadIdx.x;
    const int lane = t & 63;
    const int w = t >> 6;
    const int fl = lane & 15;
    const int kg = lane >> 4;

    short8 bfP[4][2];
    const u16* Pbase = P16 + (size_t)s * 4096;
#pragma unroll
    for (int nf = 0; nf < 4; ++nf)
#pragma unroll
        for (int kk = 0; kk < 2; ++kk)
            bfP[nf][kk] = *(const short8*)(Pbase + (nf * 16 + fl) * 64 + kk * 32 + kg * 8);

#pragma unroll
    for (int q = 0; q < 4; ++q) {
        int ci = q * 256 + t;
        int row = ci >> 3, slot = ci & 7;
        const float* src = W + (size_t)(br * 128 + row) * IN_F + s * 64 + slot * 8;
        f32x4 v0 = *(const f32x4*)src;
        f32x4 v1 = *(const f32x4*)(src + 4);
        union { short8 v; u16 e[8]; } cv;
        cv.e[0] = f2bf(v0[0]); cv.e[1] = f2bf(v0[1]); cv.e[2] = f2bf(v0[2]); cv.e[3] = f2bf(v0[3]);
        cv.e[4] = f2bf(v1[0]); cv.e[5] = f2bf(v1[1]); cv.e[6] = f2bf(v1[2]); cv.e[7] = f2bf(v1[3]);
        *(short8*)&Wst[row * 64 + (slot ^ (row & 7)) * 8] = cv.v;
    }
    __syncthreads();

    f32x4 acc1[2][4];
#pragma unroll
    for (int mf = 0; mf < 2; ++mf)
#pragma unroll
        for (int nf = 0; nf < 4; ++nf) acc1[mf][nf] = f32x4{0.f, 0.f, 0.f, 0.f};
#pragma unroll
    for (int mf = 0; mf < 2; ++mf) {
        int row = w * 32 + mf * 16 + fl;
#pragma unroll
        for (int kk = 0; kk < 2; ++kk) {
            short8 a = *(const short8*)&Wst[row * 64 + ((kk * 4 + kg) ^ (row & 7)) * 8];
#pragma unroll
            for (int nf = 0; nf < 4; ++nf)
                acc1[mf][nf] = __builtin_amdgcn_mfma_f32_16x16x32_bf16(a, bfP[nf][kk], acc1[mf][nf], 0, 0, 0);
        }
    }
#pragma unroll
    for (int mf = 0; mf < 2; ++mf)
#pragma unroll
        for (int nf = 0; nf < 4; ++nf) {
            int i = nf * 16 + fl;
            int c = w * 32 + mf * 16 + kg * 4;
            u16x4 pk;
#pragma unroll
            for (int reg = 0; reg < 4; ++reg) pk[reg] = f2bf(acc1[mf][nf][reg]);
            int slot = c >> 3, half = (c >> 2) & 1;
            *(u16x4*)&Ut[i * 128 + ((slot ^ (i & 7)) << 3) + (half << 2)] = pk;
        }
    __syncthreads();

    const int rbl = w >> 1;
    const int r_g = br * 2 + rbl;
    short8 aQ[2][2];
#pragma unroll
    for (int mf2 = 0; mf2 < 2; ++mf2) {
        int d = (w & 1) * 32 + mf2 * 16 + fl;
#pragma unroll
        for (int kk = 0; kk < 2; ++kk)
            aQ[mf2][kk] = *(const short8*)(QT16 + (size_t)r_g * 4096 + d * 64 + kk * 32 + kg * 8);
    }
    f32x4 acc2[2][4];
#pragma unroll
    for (int mf2 = 0; mf2 < 2; ++mf2)
#pragma unroll
        for (int nf = 0; nf < 4; ++nf) acc2[mf2][nf] = f32x4{0.f, 0.f, 0.f, 0.f};
#pragma unroll
    for (int kk = 0; kk < 2; ++kk)
#pragma unroll
        for (int nf = 0; nf < 4; ++nf) {
            int i = nf * 16 + fl;
            int slot = rbl * 8 + kk * 4 + kg;
            short8 bu = *(const short8*)&Ut[i * 128 + ((slot ^ (i & 7)) << 3)];
#pragma unroll
            for (int mf2 = 0; mf2 < 2; ++mf2)
                acc2[mf2][nf] = __builtin_amdgcn_mfma_f32_16x16x32_bf16(aQ[mf2][kk], bu, acc2[mf2][nf], 0, 0, 0);
        }
#pragma unroll
    for (int mf2 = 0; mf2 < 2; ++mf2)
#pragma unroll
        for (int reg = 0; reg < 4; ++reg) {
            int o_g = br * 128 + w * 32 + mf2 * 16 + kg * 4 + reg;
            int j = pinv_out[o_g];
            u16* dst = Ctp + (size_t)j * IN_F + s * 64;
#pragma unroll
            for (int nf = 0; nf < 4; ++nf)
                dst[nf * 16 + fl] = f2bf(acc2[mf2][nf][reg]);
        }
}

// ---------------- pass 5: xcast + input permutation ----------------
__global__ __launch_bounds__(512) void k_xcast_perm(const float* __restrict__ x,
                                                    const int* __restrict__ pii,
                                                    u16* __restrict__ xb) {
    __shared__ __align__(16) float xr[4096];
    const int t = threadIdx.x;
    int pv[8];
    *(i32x4*)&pv[0] = *(const i32x4*)&pii[t * 8];
    *(i32x4*)&pv[4] = *(const i32x4*)&pii[t * 8 + 4];
    for (int r = 0; r < 8; ++r) {
        size_t s = (size_t)blockIdx.x * 8 + r;
        const float* src = x + s * 4096;
        *(f32x4*)&xr[t * 4]        = *(const f32x4*)&src[t * 4];
        *(f32x4*)&xr[2048 + t * 4] = *(const f32x4*)&src[2048 + t * 4];
        __syncthreads();
        union { short8 v; u16 e[8]; } o;
#pragma unroll
        for (int j = 0; j < 8; ++j) o.e[j] = f2bf(xr[pv[j]]);
        *(short8*)&xb[s * 4096 + t * 8] = o.v;
        __syncthreads();
    }
}

// ---------------- pass 6: out = xb @ Ctp^T + bias ----------------
// 256x256 tile, BK=64, 8 waves (2Mx4N), 2 LDS buffers (128 KiB), 8-phase
// schedule (2 K-tiles/iter) with verified staging ledger (round 5), counted
// vmcnt(4) at phases 4/8 only, XOR-swizzled LDS (slot^(row&7)), setprio.
// MFMA shape: 32x32x16 (2x FLOP/instr, 2495 TF ceiling vs 2075 for 16x16).
__global__ __launch_bounds__(512, 2) void k_gemm(const u16* __restrict__ A,   // [8192][4096]
                                                 const u16* __restrict__ Bt,  // [4096][4096] N-major
                                                 const float* __restrict__ bias,
                                                 float* __restrict__ out) {
    __shared__ __align__(16) u16 lds[65536];   // buf0: A[0,16384) B[16384,32768); buf1: +32768
    const int t = threadIdx.x;
    const int lane = t & 63;
    const int wid = t >> 6;
    const int wr = wid >> 2, wc = wid & 3;

    int flat = blockIdx.y * gridDim.x + blockIdx.x;  // 0..511
    int swz  = (flat & 7) * 64 + (flat >> 3);        // XCD-contiguous chunks (512%8==0)
    int bm = swz >> 4;                               // 0..31
    int bn = swz & 15;                               // 0..15

    // staging: chunk c=t covers (row_local=t>>3, phys slot=t&7); linear LDS dest,
    // inverse-swizzled global source (XOR involution)
    const int sk = ((t & 7) ^ ((t >> 3) & 7)) * 8;
    const u16* gA = A  + (size_t)(bm * 256 + (t >> 3)) * IN_F + sk;
    const u16* gB = Bt + (size_t)(bn * 256 + (t >> 3)) * IN_F + sk;
    u16* ldst = lds + t * 8;

#define STAGE_A(buf, r0, kt) do { \
        u16* d_ = ldst + (buf) * 32768 + (r0) * 64; \
        const u16* s_ = gA + (size_t)(r0) * IN_F + (kt) * 64; \
        gload16(s_, d_); gload16(s_ + (size_t)64 * IN_F, d_ + 4096); } while (0)
#define STAGE_B(buf, r0, kt) do { \
        u16* d_ = ldst + (buf) * 32768 + 16384 + (r0) * 64; \
        const u16* s_ = gB + (size_t)(r0) * IN_F + (kt) * 64; \
        gload16(s_, d_); gload16(s_ + (size_t)64 * IN_F, d_ + 4096); } while (0)

    // 32x32x16 fragment addressing: lane holds row cl=lane&31, k = kf*16 + kh*8 + e
    const int cl = lane & 31;
    const int kh = lane >> 5;
    int askw[4];
#pragma unroll
    for (int kf = 0; kf < 4; ++kf) askw[kf] = ((kf * 2 + kh) ^ (cl & 7)) * 8;
    const int arow = (wr * 128 + cl) * 64;             // A region offset within buffer (u16)
    const int brow = 16384 + (wc * 64 + cl) * 64;      // B region offset within buffer

#define LDA(B, MI, KF) (*(const short8*)(lds + (B) + arow + (MI) * 2048 + askw[KF]))
#define LDB(B, NI, KF) (*(const short8*)(lds + (B) + brow + (NI) * 2048 + askw[KF]))

#define MQ32(AR, BR, MB, NI) do { \
        __builtin_amdgcn_s_setprio(1); \
        _Pragma("unroll") for (int kf_ = 0; kf_ < 4; ++kf_) \
        _Pragma("unroll") for (int m_ = 0; m_ < 2; ++m_) \
            acc[(MB) + m_][NI] = __builtin_amdgcn_mfma_f32_32x32x16_bf16( \
                AR[m_][kf_], BR[kf_], acc[(MB) + m_][NI], 0, 0, 0); \
        __builtin_amdgcn_s_setprio(0); } while (0)

#define BAR_LG() do { FENCE(); __builtin_amdgcn_s_barrier(); \
        asm volatile("s_waitcnt lgkmcnt(0)" ::: "memory"); } while (0)
#define BAR() do { FENCE(); __builtin_amdgcn_s_barrier(); FENCE(); } while (0)

    f32x16 acc[4][2];
#pragma unroll
    for (int m = 0; m < 4; ++m)
#pragma unroll
        for (int n = 0; n < 2; ++n)
#pragma unroll
            for (int e = 0; e < 16; ++e) acc[m][n][e] = 0.f;

    // prologue: buf0 <- K-tile 0 (all 4 halves); buf1 <- K-tile 1 (Bhalf0, Ahalf0)
    STAGE_A(0, 0, 0); STAGE_A(0, 128, 0);
    STAGE_B(0, 0, 0); STAGE_B(0, 128, 0);
    STAGE_B(1, 0, 1); STAGE_A(1, 0, 1);
    asm volatile("s_waitcnt vmcnt(4)" ::: "memory");   // buf0 fully landed
    __builtin_amdgcn_s_barrier();
    FENCE();

    short8 alo[2][4], ahi[2][4], blo[4], bhi[4];

    for (int i = 0; i < 32; ++i) {
        const int kt1 = 2 * i + 1;
        const int kn0 = (i < 31) ? 2 * i + 2 : 62;   // tail: idempotent re-stage
        const int kn1 = (i < 31) ? 2 * i + 3 : 63;

        // ---- P1: m01 x n0 (buf0) ----
#pragma unroll
        for (int m = 0; m < 2; ++m)
#pragma unroll
            for (int kf = 0; kf < 4; ++kf) alo[m][kf] = LDA(0, m, kf);
#pragma unroll
        for (int kf = 0; kf < 4; ++kf) blo[kf] = LDB(0, 0, kf);
        STAGE_A(1, 128, kt1);
        BAR_LG();
        MQ32(alo, blo, 0, 0);
        BAR();
        // ---- P2: m01 x n1 (buf0) ----
#pragma unroll
        for (int kf = 0; kf < 4; ++kf) bhi[kf] = LDB(0, 1, kf);
        STAGE_B(1, 128, kt1);
        BAR_LG();
        MQ32(alo, bhi, 0, 1);
        BAR();
        // ---- P3: m23 x n0 (buf0) ----
#pragma unroll
        for (int m = 0; m < 2; ++m)
#pragma unroll
            for (int kf = 0; kf < 4; ++kf) ahi[m][kf] = LDA(0, 2 + m, kf);
        STAGE_B(0, 0, kn0);
        BAR_LG();
        MQ32(ahi, blo, 2, 0);
        BAR();
        // ---- P4: m23 x n1 (buf0) ----
        STAGE_A(0, 0, kn0);
        asm volatile("s_waitcnt vmcnt(4)" ::: "memory");  // buf1/kt1 halves landed
        BAR();
        MQ32(ahi, bhi, 2, 1);
        BAR();
        // ---- P5: m01 x n0 (buf1) ----
#pragma unroll
        for (int m = 0; m < 2; ++m)
#pragma unroll
            for (int kf = 0; kf < 4; ++kf) alo[m][kf] = LDA(32768, m, kf);
#pragma unroll
        for (int kf = 0; kf < 4; ++kf) blo[kf] = LDB(32768, 0, kf);
        STAGE_A(0, 128, kn0);
        BAR_LG();
        MQ32(alo, blo, 0, 0);
        BAR();
        // ---- P6: m01 x n1 (buf1) ----
#pragma unroll
        for (int kf = 0; kf < 4; ++kf) bhi[kf] = LDB(32768, 1, kf);
        STAGE_B(0, 128, kn0);
        BAR_LG();
        MQ32(alo, bhi, 0, 1);
        BAR();
        // ---- P7: m23 x n0 (buf1) ----
#pragma unroll
        for (int m = 0; m < 2; ++m)
#pragma unroll
            for (int kf = 0; kf < 4; ++kf) ahi[m][kf] = LDA(32768, 2 + m, kf);
        STAGE_B(1, 0, kn1);
        BAR_LG();
        MQ32(ahi, blo, 2, 0);
        BAR();
        // ---- P8: m23 x n1 (buf1) ----
        STAGE_A(1, 0, kn1);
        asm volatile("s_waitcnt vmcnt(4)" ::: "memory");  // buf0/kn0 halves landed
        BAR();
        MQ32(ahi, bhi, 2, 1);
        BAR();
    }
    asm volatile("s_waitcnt vmcnt(0)" ::: "memory");   // drain tail stages

    // epilogue: C/D layout col=lane&31, row=(reg&3)+8*(reg>>2)+4*(lane>>5)
    const int col0 = bn * 256 + wc * 64 + cl;
    const int row0 = bm * 256 + wr * 128 + kh * 4;
    float bv[2];
    bv[0] = bias[col0];
    bv[1] = bias[col0 + 32];
#pragma unroll
    for (int mi = 0; mi < 4; ++mi)
#pragma unroll
        for (int ni = 0; ni < 2; ++ni)
#pragma unroll
            for (int r = 0; r < 16; ++r) {
                int row = row0 + mi * 32 + (r & 3) + 8 * (r >> 2);
                out[(size_t)row * OUT_F + col0 + ni * 32] = acc[mi][ni][r] + bv[ni];
            }
#undef STAGE_A
#undef STAGE_B
#undef LDA
#undef LDB
#undef MQ32
#undef BAR_LG
#undef BAR
}

extern "C" void kernel_launch(void* const* d_in, const int* in_sizes, int n_in,
                              void* d_out, int out_size, void* d_ws, size_t ws_size,
                              hipStream_t stream) {
    (void)in_sizes; (void)n_in; (void)out_size; (void)ws_size;
    const float* x    = (const float*)d_in[0];
    const float* Ro   = (const float*)d_in[1];
    const float* Ri   = (const float*)d_in[2];
    const float* W    = (const float*)d_in[3];
    const float* bias = (const float*)d_in[4];
    const int* perm_in_inv = (const int*)d_in[5];
    const int* perm_out    = (const int*)d_in[6];
    float* out = (float*)d_out;

    char* ws = (char*)d_ws;
    float* Rout   = (float*)(ws);                               // 1 MiB
    u16*   P16    = (u16*)(ws + (1ull << 20));                  // 512 KiB
    u16*   QT16   = (u16*)(ws + (1ull << 20) + (1 << 19));      // 512 KiB
    int*   pinvo  = (int*)(ws + (2ull << 20));                  // 16 KiB
    float* bfinal = (float*)(ws + (2ull << 20) + (1 << 16));    // 16 KiB
    u16*   Ctp    = (u16*)(ws + (4ull << 20));                  // 32 MiB
    u16*   xb     = (u16*)(ws + (36ull << 20));                 // 64 MiB

    k_inv_perm<<<16, 256, 0, stream>>>(perm_out, pinvo);
    k_cayley<<<128, 256, 0, stream>>>(Ro, Ri, Rout, QT16, P16);
    k_bias<<<16, 256, 0, stream>>>(bias, Rout, perm_out, bfinal);
    k_fold<<<dim3(64, 32), 256, 0, stream>>>(W, P16, QT16, pinvo, Ctp);
    k_xcast_perm<<<1024, 512, 0, stream>>>(x, perm_in_inv, xb);
    k_gemm<<<dim3(16, 32), 512, 0, stream>>>(xb, Ctp, bfinal, out);
}

// Round 7
// 318.235 us; speedup vs baseline: 1.1294x; 1.1294x over previous
//
#include <hip/hip_runtime.h>
#include <stdint.h>

#define IN_F 4096
#define OUT_F 4096
#define NTRI 2016

typedef unsigned short u16;
typedef __attribute__((ext_vector_type(8))) short short8;
typedef __attribute__((ext_vector_type(4))) float f32x4;
typedef __attribute__((ext_vector_type(4))) int i32x4;
typedef __attribute__((ext_vector_type(4))) unsigned short u16x4;

__device__ __forceinline__ u16 f2bf(float f) {
    uint32_t u = __builtin_bit_cast(uint32_t, f);
    u = (u + 0x7FFFu + ((u >> 16) & 1u)) >> 16;   // round-to-nearest-even
    return (u16)u;
}

__device__ __forceinline__ void gload16(const void* g, void* l) {
    __builtin_amdgcn_global_load_lds((__attribute__((address_space(1))) void*)g,
                                     (__attribute__((address_space(3))) void*)l,
                                     16, 0, 0);
}

// ================= K1: cayley (blocks 0..127) + perm-invert (block 128) =================
__global__ __launch_bounds__(256) void k_prep(const float* __restrict__ Ro,
                                              const float* __restrict__ Ri,
                                              const int* __restrict__ perm_out,
                                              float* __restrict__ Rout,
                                              u16* __restrict__ QT16,
                                              u16* __restrict__ P16,
                                              int* __restrict__ pinv_out) {
    const int b = blockIdx.x;
    const int t = threadIdx.x;
    if (b == 128) {
#pragma unroll
        for (int e = 0; e < 16; ++e) {
            int i = e * 256 + t;
            pinv_out[perm_out[i]] = i;
        }
        return;
    }
    __shared__ __align__(16) float Qs[64 * 64];
    __shared__ __align__(16) float Ps[64 * 68];
    __shared__ __align__(16) float Ts[64 * 68];
    const float* vec = (b < 64) ? (Ro + (size_t)b * NTRI) : (Ri + (size_t)(b - 64) * NTRI);
    int tr = t >> 4, tc = t & 15;
#pragma unroll
    for (int e = 0; e < 16; ++e) {
        int el = e * 256 + t;
        int i = el >> 6, j = el & 63;
        float q = 0.f;
        if (i < j) q =  vec[i * 63 - (i * (i - 1)) / 2 + (j - i - 1)];
        if (i > j) q = -vec[j * 63 - (j * (j - 1)) / 2 + (i - j - 1)];
        Qs[el] = q;
    }
    __syncthreads();
    float a2[4][4], a3[4][4], a4[4][4];
#pragma unroll
    for (int i = 0; i < 4; ++i)
#pragma unroll
        for (int j = 0; j < 4; ++j) { a2[i][j] = 0.f; a3[i][j] = 0.f; a4[i][j] = 0.f; }
    for (int k = 0; k < 64; ++k) {
        f32x4 qa = *(const f32x4*)&Qs[k * 64 + tr * 4];
        f32x4 qb = *(const f32x4*)&Qs[k * 64 + tc * 4];
#pragma unroll
        for (int i = 0; i < 4; ++i)
#pragma unroll
            for (int j = 0; j < 4; ++j) a2[i][j] -= qa[i] * qb[j];
    }
#pragma unroll
    for (int i = 0; i < 4; ++i)
#pragma unroll
        for (int j = 0; j < 4; ++j) Ps[(tr * 4 + i) * 68 + tc * 4 + j] = a2[i][j];
    __syncthreads();
    for (int k = 0; k < 64; ++k) {
        f32x4 pa = *(const f32x4*)&Ps[k * 68 + tr * 4];
        f32x4 qb = *(const f32x4*)&Qs[k * 64 + tc * 4];
#pragma unroll
        for (int i = 0; i < 4; ++i)
#pragma unroll
            for (int j = 0; j < 4; ++j) a3[i][j] += pa[i] * qb[j];
    }
#pragma unroll
    for (int i = 0; i < 4; ++i)
#pragma unroll
        for (int j = 0; j < 4; ++j) Ts[(tc * 4 + j) * 68 + tr * 4 + i] = -a3[i][j];  // Ts[k][i]=Q3[k][i]
    __syncthreads();
    for (int k = 0; k < 64; ++k) {
        f32x4 ta = *(const f32x4*)&Ts[k * 68 + tr * 4];
        f32x4 qb = *(const f32x4*)&Qs[k * 64 + tc * 4];
#pragma unroll
        for (int i = 0; i < 4; ++i)
#pragma unroll
            for (int j = 0; j < 4; ++j) a4[i][j] -= ta[i] * qb[j];
    }
    if (b < 64) {
        float* dst = Rout + (size_t)b * 4096;
        u16* qt = QT16 + (size_t)b * 4096;
#pragma unroll
        for (int i = 0; i < 4; ++i) {
            int gi = tr * 4 + i;
            f32x4 q4 = *(const f32x4*)&Qs[gi * 64 + tc * 4];
            f32x4 o;
#pragma unroll
            for (int j = 0; j < 4; ++j) {
                int gj = tc * 4 + j;
                o[j] = 2.f * (q4[j] + a2[i][j] + a3[i][j] + a4[i][j]) + ((gi == gj) ? 1.f : 0.f);
            }
            *(f32x4*)&dst[gi * 64 + tc * 4] = o;
#pragma unroll
            for (int j = 0; j < 4; ++j) qt[(tc * 4 + j) * 64 + gi] = f2bf(o[j]);  // QT[d][c]=R[c][d]
        }
    } else {
        u16* p = P16 + (size_t)(b - 64) * 4096;
#pragma unroll
        for (int i = 0; i < 4; ++i) {
            int gi = tr * 4 + i;
            f32x4 q4 = *(const f32x4*)&Qs[gi * 64 + tc * 4];
            u16x4 pk;
#pragma unroll
            for (int j = 0; j < 4; ++j) {
                int gj = tc * 4 + j;
                float v = 2.f * (q4[j] + a2[i][j] + a3[i][j] + a4[i][j]) + ((gi == gj) ? 1.f : 0.f);
                pk[j] = f2bf(v);
            }
            *(u16x4*)&p[gi * 64 + tc * 4] = pk;
        }
    }
}

// ================= K2: fold (0..2047) + xcast_perm (2048..3071) + bias (3072..3087) ======
__global__ __launch_bounds__(256) void k_work(const float* __restrict__ W,
                                              const u16* __restrict__ P16,
                                              const u16* __restrict__ QT16,
                                              const int* __restrict__ pinv_out,
                                              const float* __restrict__ x,
                                              const int* __restrict__ pii,
                                              const float* __restrict__ bias,
                                              const float* __restrict__ Rout,
                                              const int* __restrict__ perm_out,
                                              u16* __restrict__ Ctp,
                                              u16* __restrict__ xb,
                                              float* __restrict__ bfinal) {
    const int fb = blockIdx.x;
    const int t = threadIdx.x;
    if (fb < 2048) {
        // ---------------- fused MFMA fold ----------------
        __shared__ __align__(16) u16 Wst[128 * 64];   // swizzled bf16 W tile
        __shared__ __align__(16) u16 Ut[64 * 128];    // Ut[i][c] swizzled
        const int s = fb & 63;
        const int br = fb >> 6;
        const int lane = t & 63;
        const int w = t >> 6;
        const int fl = lane & 15;
        const int kg = lane >> 4;

        short8 bfP[4][2];
        const u16* Pbase = P16 + (size_t)s * 4096;
#pragma unroll
        for (int nf = 0; nf < 4; ++nf)
#pragma unroll
            for (int kk = 0; kk < 2; ++kk)
                bfP[nf][kk] = *(const short8*)(Pbase + (nf * 16 + fl) * 64 + kk * 32 + kg * 8);

#pragma unroll
        for (int q = 0; q < 4; ++q) {
            int ci = q * 256 + t;
            int row = ci >> 3, slot = ci & 7;
            const float* src = W + (size_t)(br * 128 + row) * IN_F + s * 64 + slot * 8;
            f32x4 v0 = *(const f32x4*)src;
            f32x4 v1 = *(const f32x4*)(src + 4);
            union { short8 v; u16 e[8]; } cv;
            cv.e[0] = f2bf(v0[0]); cv.e[1] = f2bf(v0[1]); cv.e[2] = f2bf(v0[2]); cv.e[3] = f2bf(v0[3]);
            cv.e[4] = f2bf(v1[0]); cv.e[5] = f2bf(v1[1]); cv.e[6] = f2bf(v1[2]); cv.e[7] = f2bf(v1[3]);
            *(short8*)&Wst[row * 64 + (slot ^ (row & 7)) * 8] = cv.v;
        }
        __syncthreads();

        f32x4 acc1[2][4];
#pragma unroll
        for (int mf = 0; mf < 2; ++mf)
#pragma unroll
            for (int nf = 0; nf < 4; ++nf) acc1[mf][nf] = f32x4{0.f, 0.f, 0.f, 0.f};
#pragma unroll
        for (int mf = 0; mf < 2; ++mf) {
            int row = w * 32 + mf * 16 + fl;
#pragma unroll
            for (int kk = 0; kk < 2; ++kk) {
                short8 a = *(const short8*)&Wst[row * 64 + ((kk * 4 + kg) ^ (row & 7)) * 8];
#pragma unroll
                for (int nf = 0; nf < 4; ++nf)
                    acc1[mf][nf] = __builtin_amdgcn_mfma_f32_16x16x32_bf16(a, bfP[nf][kk], acc1[mf][nf], 0, 0, 0);
            }
        }
#pragma unroll
        for (int mf = 0; mf < 2; ++mf)
#pragma unroll
            for (int nf = 0; nf < 4; ++nf) {
                int i = nf * 16 + fl;
                int c = w * 32 + mf * 16 + kg * 4;
                u16x4 pk;
#pragma unroll
                for (int reg = 0; reg < 4; ++reg) pk[reg] = f2bf(acc1[mf][nf][reg]);
                int slot = c >> 3, half = (c >> 2) & 1;
                *(u16x4*)&Ut[i * 128 + ((slot ^ (i & 7)) << 3) + (half << 2)] = pk;
            }
        __syncthreads();

        const int rbl = w >> 1;
        const int r_g = br * 2 + rbl;
        short8 aQ[2][2];
#pragma unroll
        for (int mf2 = 0; mf2 < 2; ++mf2) {
            int d = (w & 1) * 32 + mf2 * 16 + fl;
#pragma unroll
            for (int kk = 0; kk < 2; ++kk)
                aQ[mf2][kk] = *(const short8*)(QT16 + (size_t)r_g * 4096 + d * 64 + kk * 32 + kg * 8);
        }
        f32x4 acc2[2][4];
#pragma unroll
        for (int mf2 = 0; mf2 < 2; ++mf2)
#pragma unroll
            for (int nf = 0; nf < 4; ++nf) acc2[mf2][nf] = f32x4{0.f, 0.f, 0.f, 0.f};
#pragma unroll
        for (int kk = 0; kk < 2; ++kk)
#pragma unroll
            for (int nf = 0; nf < 4; ++nf) {
                int i = nf * 16 + fl;
                int slot = rbl * 8 + kk * 4 + kg;
                short8 bu = *(const short8*)&Ut[i * 128 + ((slot ^ (i & 7)) << 3)];
#pragma unroll
                for (int mf2 = 0; mf2 < 2; ++mf2)
                    acc2[mf2][nf] = __builtin_amdgcn_mfma_f32_16x16x32_bf16(aQ[mf2][kk], bu, acc2[mf2][nf], 0, 0, 0);
            }
#pragma unroll
        for (int mf2 = 0; mf2 < 2; ++mf2)
#pragma unroll
            for (int reg = 0; reg < 4; ++reg) {
                int o_g = br * 128 + w * 32 + mf2 * 16 + kg * 4 + reg;
                int j = pinv_out[o_g];
                u16* dst = Ctp + (size_t)j * IN_F + s * 64;
#pragma unroll
                for (int nf = 0; nf < 4; ++nf)
                    dst[nf * 16 + fl] = f2bf(acc2[mf2][nf][reg]);
            }
    } else if (fb < 3072) {
        // ---------------- xcast + input permutation (256 threads, 8 rows/block) --------
        __shared__ __align__(16) float xr[4096];
        const int blk = fb - 2048;
        int pv[16];
#pragma unroll
        for (int q = 0; q < 4; ++q) *(i32x4*)&pv[q * 4] = *(const i32x4*)&pii[t * 16 + q * 4];
        for (int r = 0; r < 8; ++r) {
            size_t srow = (size_t)blk * 8 + r;
            const float* src = x + srow * 4096;
#pragma unroll
            for (int q = 0; q < 4; ++q)
                *(f32x4*)&xr[q * 1024 + t * 4] = *(const f32x4*)&src[q * 1024 + t * 4];
            __syncthreads();
            union { short8 v; u16 e[8]; } o0, o1;
#pragma unroll
            for (int j = 0; j < 8; ++j) { o0.e[j] = f2bf(xr[pv[j]]); o1.e[j] = f2bf(xr[pv[8 + j]]); }
            *(short8*)&xb[srow * 4096 + t * 16] = o0.v;
            *(short8*)&xb[srow * 4096 + t * 16 + 8] = o1.v;
            __syncthreads();
        }
    } else {
        // ---------------- bias: bfinal[j] = (bias . R_out_bd)[perm_out[j]] ------------
        int j = (fb - 3072) * 256 + t;
        int o = perm_out[j];
        int r = o >> 6, d = o & 63;
        const float* Rb = Rout + (size_t)r * 4096;
        const float* bb = bias + r * 64;
        float s = 0.f;
        for (int c = 0; c < 64; ++c) s += bb[c] * Rb[c * 64 + d];
        bfinal[j] = s;
    }
}

// ================= K3: GEMM — round-2 structure (best measured) =================
// 256x256 tile, BK=32, 8 waves (2Mx4N), 4 LDS buffers (128 KiB), 3-tile-deep
// counted-vmcnt prefetch, XOR-swizzled LDS (pre-swizzled global source), setprio.
__global__ __launch_bounds__(512, 2) void k_gemm(const u16* __restrict__ A,   // [8192][4096]
                                                 const u16* __restrict__ Bt,  // [4096][4096] N-major
                                                 const float* __restrict__ bias,
                                                 float* __restrict__ out) {
    __shared__ __align__(16) u16 lds[65536];   // 128 KiB: buf b at b*16384 (A:8192, B:8192 u16)
    const int t = threadIdx.x;
    const int lane = t & 63;
    const int wid = t >> 6;
    const int wr = wid >> 2, wc = wid & 3;

    int flat = blockIdx.y * gridDim.x + blockIdx.x;  // 0..511
    int swz  = (flat & 7) * 64 + (flat >> 3);        // XCD-contiguous work chunks
    int bm = swz >> 4;                               // 0..31
    int bn = swz & 15;                               // 0..15

    const int srow = t >> 2;                          // 0..127
    const int sks  = (t & 3) ^ ((t >> 3) & 3);
    const u16* sA0 = A  + (size_t)(bm * 256 + srow) * IN_F + sks * 8;
    const u16* sA1 = sA0 + (size_t)128 * IN_F;
    const u16* sB0 = Bt + (size_t)(bn * 256 + srow) * IN_F + sks * 8;
    const u16* sB1 = sB0 + (size_t)128 * IN_F;
    u16* dA = lds + t * 8;            // + buf*16384 (A region)
    u16* dB = lds + 8192 + t * 8;     // + buf*16384 (B region)

    const int frow = lane & 15;
    const int kg = lane >> 4;
    const int swzr = kg ^ ((frow >> 1) & 3);
    const int aoff = (wr * 128 + frow) * 32 + swzr * 8;           // u16 units
    const int boff = 8192 + (wc * 64 + frow) * 32 + swzr * 8;

    f32x4 acc[8][4];
#pragma unroll
    for (int m = 0; m < 8; ++m)
#pragma unroll
        for (int n = 0; n < 4; ++n) acc[m][n] = f32x4{0.f, 0.f, 0.f, 0.f};

    // prologue: stage tiles 0,1,2 (12 loads in flight)
#pragma unroll
    for (int p = 0; p < 3; ++p) {
        int off = p * 32;
        int bb = p * 16384;
        gload16(sA0 + off, dA + bb); gload16(sA1 + off, dA + bb + 4096);
        gload16(sB0 + off, dB + bb); gload16(sB1 + off, dB + bb + 4096);
    }
    asm volatile("s_waitcnt vmcnt(8)" ::: "memory");   // tile 0 landed
    __builtin_amdgcn_s_barrier();

    for (int t4 = 0; t4 < 128; t4 += 4) {
#pragma unroll
        for (int u = 0; u < 4; ++u) {
            const int kt = t4 + u;
            const u16* base = lds + u * 16384;
            short8 af[8], bf[4];
            const u16* pa = base + aoff;
            const u16* pb = base + boff;
#pragma unroll
            for (int m = 0; m < 8; ++m) af[m] = *(const short8*)(pa + m * 512);
#pragma unroll
            for (int n = 0; n < 4; ++n) bf[n] = *(const short8*)(pb + n * 512);
            // prefetch tile kt+3 into buf (kt+3)&3 (that buf's reads finished last iter)
            {
                int ts = kt + 3;
                int tsc = ts < 128 ? ts : 124;       // tail: dummy (never-read) loads keep vmcnt uniform
                int off = tsc * 32;
                int bb = ((kt + 3) & 3) * 16384;
                gload16(sA0 + off, dA + bb); gload16(sA1 + off, dA + bb + 4096);
                gload16(sB0 + off, dB + bb); gload16(sB1 + off, dB + bb + 4096);
            }
            __builtin_amdgcn_s_setprio(1);
#pragma unroll
            for (int m = 0; m < 8; ++m)
#pragma unroll
                for (int n = 0; n < 4; ++n)
                    acc[m][n] = __builtin_amdgcn_mfma_f32_16x16x32_bf16(af[m], bf[n], acc[m][n], 0, 0, 0);
            __builtin_amdgcn_s_setprio(0);
            asm volatile("s_waitcnt vmcnt(8)" ::: "memory");  // tile kt+1 landed; 8 stay in flight
            __builtin_amdgcn_s_barrier();
        }
    }
    asm volatile("s_waitcnt vmcnt(0)" ::: "memory");   // drain dummies before LDS dealloc

    const int col0 = bn * 256 + wc * 64 + frow;
    const int row0 = bm * 256 + wr * 128 + kg * 4;
    float bv[4];
#pragma unroll
    for (int n = 0; n < 4; ++n) bv[n] = bias[col0 + n * 16];
#pragma unroll
    for (int m = 0; m < 8; ++m)
#pragma unroll
        for (int n = 0; n < 4; ++n)
#pragma unroll
            for (int i = 0; i < 4; ++i)
                out[(size_t)(row0 + m * 16 + i) * OUT_F + col0 + n * 16] = acc[m][n][i] + bv[n];
}

extern "C" void kernel_launch(void* const* d_in, const int* in_sizes, int n_in,
                              void* d_out, int out_size, void* d_ws, size_t ws_size,
                              hipStream_t stream) {
    (void)in_sizes; (void)n_in; (void)out_size; (void)ws_size;
    const float* x    = (const float*)d_in[0];
    const float* Ro   = (const float*)d_in[1];
    const float* Ri   = (const float*)d_in[2];
    const float* W    = (const float*)d_in[3];
    const float* bias = (const float*)d_in[4];
    const int* perm_in_inv = (const int*)d_in[5];
    const int* perm_out    = (const int*)d_in[6];
    float* out = (float*)d_out;

    char* ws = (char*)d_ws;
    float* Rout   = (float*)(ws);                               // 1 MiB
    u16*   P16    = (u16*)(ws + (1ull << 20));                  // 512 KiB
    u16*   QT16   = (u16*)(ws + (1ull << 20) + (1 << 19));      // 512 KiB
    int*   pinvo  = (int*)(ws + (2ull << 20));                  // 16 KiB
    float* bfinal = (float*)(ws + (2ull << 20) + (1 << 16));    // 16 KiB
    u16*   Ctp    = (u16*)(ws + (4ull << 20));                  // 32 MiB
    u16*   xb     = (u16*)(ws + (36ull << 20));                 // 64 MiB

    k_prep<<<129, 256, 0, stream>>>(Ro, Ri, perm_out, Rout, QT16, P16, pinvo);
    k_work<<<3088, 256, 0, stream>>>(W, P16, QT16, pinvo, x, perm_in_inv, bias, Rout,
                                     perm_out, Ctp, xb, bfinal);
    k_gemm<<<dim3(16, 32), 512, 0, stream>>>(xb, Ctp, bfinal, out);
}